// Round 11
// baseline (668.298 us; speedup 1.0000x reference)
//
#include <hip/hip_runtime.h>
#include <hip/hip_bf16.h>
#include <math.h>

#define DIM 768
#define NHEADS 12
#define HD 64
#define SEQ 4096
#define KSPLIT 4

typedef __bf16 bf16x8 __attribute__((ext_vector_type(8)));
typedef float f32x4 __attribute__((ext_vector_type(4)));

// Native bf16 convert (RNE; gfx950 has HW cvt, compiler may pack pairs)
__device__ inline ushort f2bf(float f) {
    __bf16 b = (__bf16)f;
    union { __bf16 b; ushort u; } v; v.b = b;
    return v.u;
}

// ---------------------------------------------------------------------------
// f32 -> bf16 bulk convert (16B loads / 8B stores), exact-grid.
// ---------------------------------------------------------------------------
__global__ __launch_bounds__(256)
void cvt_bf16(const float* __restrict__ src, ushort* __restrict__ dst, int n4)
{
    const int i = blockIdx.x * 256 + threadIdx.x;
    if (i >= n4) return;
    const float4 v = ((const float4*)src)[i];
    ushort4 w;
    w.x = f2bf(v.x); w.y = f2bf(v.y); w.z = f2bf(v.z); w.w = f2bf(v.w);
    ((ushort4*)dst)[i] = w;
}

// ---------------------------------------------------------------------------
// RoPE table: tab[n][j] = (cos, sin) of n * 10000^(-j/32), j in [0,32).
// ---------------------------------------------------------------------------
__global__ __launch_bounds__(256)
void rope_tab_k(float2* __restrict__ tab)
{
    const int idx = blockIdx.x * 256 + threadIdx.x;   // 4096*32
    const int j = idx & 31;
    const int n = idx >> 5;
    const float invf = (float)pow(10000.0, -(double)j / 32.0);
    const float ang  = (float)n * invf;               // f32 (matches ref freqs)
    double s, c;
    sincos((double)ang, &s, &c);
    tab[idx] = make_float2((float)c, (float)s);
}

// ---------------------------------------------------------------------------
// QKV GEMM (bf16 in) + fused RoPE + layout:
//   t=0 (q): RoPE, *0.125, bf16 -> Qb[h][n][d]
//   t=1 (k): RoPE, bf16 -> Kb[h][n][d]
//   t=2 (v): bf16 -> Vp[h][d][64T + s], key-slot permuted (flash P order)
// Staging is pure 16B bf16 copies (pre-converted inputs; no cvt VALU).
// ---------------------------------------------------------------------------
__global__ __launch_bounds__(256)
void gemm_qkv(const ushort* __restrict__ A, const ushort* __restrict__ B,
              const float2* __restrict__ tab,
              ushort* __restrict__ Qb, ushort* __restrict__ Kb,
              ushort* __restrict__ Vp)
{
    constexpr int BM = 128, BN = 128, BK = 64, PAD = 8;
    __shared__ ushort Ah[BM][BK + PAD];
    __shared__ ushort Bh[BN][BK + PAD];

    const int t    = threadIdx.x;
    const int lane = t & 63;
    const int wv   = t >> 6;
    const int wm   = (wv >> 1) * 64;
    const int wn   = (wv & 1) * 64;
    const int m0   = blockIdx.y * BM;
    const int n0   = blockIdx.x * BN;

    f32x4 acc[4][4] = {};

    const int srow = t >> 3;          // 0..31
    const int sseg = (t & 7) * 8;     // bf16 16B chunks

    for (int k0 = 0; k0 < DIM; k0 += BK) {
        #pragma unroll
        for (int i = 0; i < 4; ++i) {
            const int row = srow + i * 32;
            *(float4*)&Ah[row][sseg] =
                *(const float4*)&A[(size_t)(m0 + row) * DIM + k0 + sseg];
            *(float4*)&Bh[row][sseg] =
                *(const float4*)&B[(size_t)(n0 + row) * DIM + k0 + sseg];
        }
        __syncthreads();

        #pragma unroll
        for (int ks = 0; ks < BK; ks += 32) {
            const int koff = ks + ((lane >> 4) << 3);
            const int rs = lane & 15;
            bf16x8 af[4], bf[4];
            #pragma unroll
            for (int i = 0; i < 4; ++i) {
                af[i] = *(const bf16x8*)&Ah[wm + i * 16 + rs][koff];
                bf[i] = *(const bf16x8*)&Bh[wn + i * 16 + rs][koff];
            }
            #pragma unroll
            for (int i = 0; i < 4; ++i)
                #pragma unroll
                for (int j = 0; j < 4; ++j)
                    acc[i][j] = __builtin_amdgcn_mfma_f32_16x16x32_bf16(
                        af[i], bf[j], acc[i][j], 0, 0, 0);
        }
        __syncthreads();
    }

    const int rsel  = lane & 15;
    const int quad  = lane >> 4;
    const int rbase = m0 + wm + (quad << 2);
    const int c0    = n0 + wn;          // 64-aligned -> one (t,h) per wave
    const int tt    = c0 / DIM;
    const int h     = (c0 % DIM) >> 6;

    if (tt == 2) {
        // key kappa (within 64-tile) = 16i + 4quad + r -> slot 16quad + 4r + i
        const int T = (m0 + wm) >> 6;
        #pragma unroll
        for (int j = 0; j < 4; ++j) {
            const int d = rsel + 16 * j;
            ushort vv[16];
            #pragma unroll
            for (int r = 0; r < 4; ++r)
                #pragma unroll
                for (int i = 0; i < 4; ++i)
                    vv[4 * r + i] = f2bf(acc[i][j][r]);
            ushort* dst = &Vp[((size_t)h * HD + d) * SEQ + T * 64 + 16 * quad];
            *(float4*)&dst[0] = *(const float4*)&vv[0];
            *(float4*)&dst[8] = *(const float4*)&vv[8];
        }
    } else {
        ushort* dstb = (tt == 0 ? Qb : Kb) + (size_t)h * SEQ * HD;
        const float qs = (tt == 0) ? 0.125f : 1.0f;
        #pragma unroll
        for (int i = 0; i < 4; ++i)
            #pragma unroll
            for (int r = 0; r < 4; ++r) {
                const int n = rbase + i * 16 + r;
                #pragma unroll
                for (int j = 0; j < 2; ++j) {
                    const float a = acc[i][j][r];
                    const float b = acc[i][j + 2][r];
                    const float2 cs2 = tab[n * 32 + rsel + 16 * j];
                    dstb[(size_t)n * HD + rsel + 16 * j]      = f2bf((a * cs2.x - b * cs2.y) * qs);
                    dstb[(size_t)n * HD + rsel + 16 * j + 32] = f2bf((b * cs2.x + a * cs2.y) * qs);
                }
            }
    }
}

// ---------------------------------------------------------------------------
// MFMA flash attention, LDS-staged K/V, split-K, no-max softmax.
// Block = 4 waves x 32 q-rows = 128 rows. LDS = 26.1 KB -> 6 blocks/CU
// (matches the 6-block/CU grid; the 34.8 KB version ran a 4+2 two-round
// dispatch). P buffer (16 rows/wave) is reused across the two M-halves.
// ---------------------------------------------------------------------------
__global__ __launch_bounds__(256, 6)
void flash_mfma(const ushort* __restrict__ Qb, const ushort* __restrict__ Kb,
                const ushort* __restrict__ Vp,
                float* __restrict__ Opart, float* __restrict__ lpart)
{
    __shared__ ushort Ks[64][68];      // [key][d]
    __shared__ ushort Vs[64][68];      // [d][slot]
    __shared__ ushort Pl[4][16][68];   // per-wave P, [row][slot], reused per mi

    const int t    = threadIdx.x;
    const int lane = t & 63;
    const int wv   = t >> 6;
    const int rsel = lane & 15;
    const int quad = lane >> 4;
    const int h    = blockIdx.y;
    const int part = blockIdx.z;
    const int q0   = blockIdx.x * 128 + wv * 32;
    const int Tbeg = (part * (SEQ / KSPLIT)) >> 6;
    const int Tend = Tbeg + (SEQ / KSPLIT) / 64;

    const int crow = t >> 2;           // 0..63 staging row
    const int ccol = (t & 3) * 16;     // 0/16/32/48 ushorts (2x16B per thread)

    // Q A-frags (persistent)
    bf16x8 aq[2][2];
    #pragma unroll
    for (int mi = 0; mi < 2; ++mi)
        #pragma unroll
        for (int ks = 0; ks < 2; ++ks)
            aq[mi][ks] = *(const bf16x8*)&Qb[((size_t)h * SEQ + q0 + 16 * mi + rsel) * HD
                                             + ks * 32 + quad * 8];

    f32x4 accO[2][4] = {};
    float lsum[2][4] = {};

    for (int T = Tbeg; T < Tend; ++T) {
        __syncthreads();               // prior tile's LDS reads done
        {   // coalesced staging: 4 consecutive threads cover one 128B row
            const ushort* ksrc = &Kb[((size_t)h * SEQ + T * 64 + crow) * HD + ccol];
            *(float4*)&Ks[crow][ccol]     = *(const float4*)&ksrc[0];
            *(float4*)&Ks[crow][ccol + 8] = *(const float4*)&ksrc[8];
            const ushort* vsrc = &Vp[((size_t)h * HD + crow) * SEQ + T * 64 + ccol];
            *(float4*)&Vs[crow][ccol]     = *(const float4*)&vsrc[0];
            *(float4*)&Vs[crow][ccol + 8] = *(const float4*)&vsrc[8];
        }
        __syncthreads();

        // K and V B-frags from LDS (shared across both M-halves)
        bf16x8 bk[4][2], bv[4][2];
        #pragma unroll
        for (int n = 0; n < 4; ++n)
            #pragma unroll
            for (int ks = 0; ks < 2; ++ks) {
                bk[n][ks] = *(const bf16x8*)&Ks[16 * n + rsel][32 * ks + quad * 8];
                bv[n][ks] = *(const bf16x8*)&Vs[16 * n + rsel][32 * ks + quad * 8];
            }

        #pragma unroll
        for (int mi = 0; mi < 2; ++mi) {
            f32x4 accS[4] = {};
            #pragma unroll
            for (int ks = 0; ks < 2; ++ks)
                #pragma unroll
                for (int n = 0; n < 4; ++n)
                    accS[n] = __builtin_amdgcn_mfma_f32_16x16x32_bf16(
                        aq[mi][ks], bk[n][ks], accS[n], 0, 0, 0);

            // P = exp(S); packed write, slot s = 4rsel + n (key = 16n + rsel)
            #pragma unroll
            for (int r = 0; r < 4; ++r) {
                const float p0 = __expf(accS[0][r]);
                const float p1 = __expf(accS[1][r]);
                const float p2 = __expf(accS[2][r]);
                const float p3 = __expf(accS[3][r]);
                ushort4 pw;
                pw.x = f2bf(p0); pw.y = f2bf(p1);
                pw.z = f2bf(p2); pw.w = f2bf(p3);
                *(ushort4*)&Pl[wv][4 * quad + r][4 * rsel] = pw;
                lsum[mi][r] += (p0 + p1) + (p2 + p3);
            }

            // wave-private LDS RAW: drain writes before A-frag reads
            asm volatile("s_waitcnt lgkmcnt(0)" ::: "memory");

            bf16x8 ap[2];
            ap[0] = *(const bf16x8*)&Pl[wv][rsel][quad * 8];
            ap[1] = *(const bf16x8*)&Pl[wv][rsel][32 + quad * 8];
            #pragma unroll
            for (int ks = 0; ks < 2; ++ks)
                #pragma unroll
                for (int j = 0; j < 4; ++j)
                    accO[mi][j] = __builtin_amdgcn_mfma_f32_16x16x32_bf16(
                        ap[ks], bv[j][ks], accO[mi][j], 0, 0, 0);
        }
    }

    // one-time l reduction across rsel lanes
    #pragma unroll
    for (int mi = 0; mi < 2; ++mi)
        #pragma unroll
        for (int r = 0; r < 4; ++r) {
            float s = lsum[mi][r];
            s += __shfl_xor(s, 1);
            s += __shfl_xor(s, 2);
            s += __shfl_xor(s, 4);
            s += __shfl_xor(s, 8);
            lsum[mi][r] = s;
        }

    float* Ob = Opart + ((size_t)part * NHEADS + h) * SEQ * HD;
    float* lb = lpart + ((size_t)part * NHEADS + h) * SEQ;
    #pragma unroll
    for (int mi = 0; mi < 2; ++mi)
        #pragma unroll
        for (int r = 0; r < 4; ++r) {
            const int n = q0 + 16 * mi + 4 * quad + r;
            #pragma unroll
            for (int j = 0; j < 4; ++j)
                Ob[(size_t)n * HD + 16 * j + rsel] = accO[mi][j][r];
            if (rsel == 0) lb[n] = lsum[mi][r];
        }
}

// ---------------------------------------------------------------------------
// Split-K merge: AO[n][h*64+d] = (sum_p Opart) / (sum_p l), bf16.
// ---------------------------------------------------------------------------
__global__ __launch_bounds__(256)
void merge_k(const float* __restrict__ Opart, const float* __restrict__ lpart,
             ushort* __restrict__ AO)
{
    const int idx = blockIdx.x * 256 + threadIdx.x;
    const int dg = idx & 15;
    const int n  = (idx >> 4) & (SEQ - 1);
    const int h  = idx >> 16;

    float4 o = make_float4(0.f, 0.f, 0.f, 0.f);
    float l = 0.f;
    #pragma unroll
    for (int p = 0; p < KSPLIT; ++p) {
        const float4 v = *(const float4*)&Opart[(((size_t)p * NHEADS + h) * SEQ + n) * HD + dg * 4];
        o.x += v.x; o.y += v.y; o.z += v.z; o.w += v.w;
        l += lpart[((size_t)p * NHEADS + h) * SEQ + n];
    }
    const float inv = 1.f / l;
    ushort4 w;
    w.x = f2bf(o.x * inv); w.y = f2bf(o.y * inv);
    w.z = f2bf(o.z * inv); w.w = f2bf(o.w * inv);
    *(ushort4*)&AO[(size_t)n * DIM + h * HD + dg * 4] = w;
}

// ---------------------------------------------------------------------------
// Proj GEMM: out = attnout(bf16) @ proj_wb(bf16)^T + proj_b(f32), f32 out.
// ---------------------------------------------------------------------------
__global__ __launch_bounds__(256)
void gemm_proj(const ushort* __restrict__ A, const ushort* __restrict__ B,
               const float* __restrict__ bias, float* __restrict__ out)
{
    constexpr int BM = 128, BN = 128, BK = 64, PAD = 8;
    __shared__ ushort As[BM][BK + PAD];
    __shared__ ushort Bs[BN][BK + PAD];

    const int t    = threadIdx.x;
    const int lane = t & 63;
    const int wv   = t >> 6;
    const int wm   = (wv >> 1) * 64;
    const int wn   = (wv & 1) * 64;
    const int m0   = blockIdx.y * BM;
    const int n0   = blockIdx.x * BN;

    f32x4 acc[4][4] = {};

    const int srow = t >> 3;
    const int sseg = (t & 7) * 8;

    for (int k0 = 0; k0 < DIM; k0 += BK) {
        #pragma unroll
        for (int i = 0; i < 4; ++i) {
            const int row = srow + i * 32;
            *(float4*)&As[row][sseg] =
                *(const float4*)&A[(size_t)(m0 + row) * DIM + k0 + sseg];
            *(float4*)&Bs[row][sseg] =
                *(const float4*)&B[(size_t)(n0 + row) * DIM + k0 + sseg];
        }
        __syncthreads();

        #pragma unroll
        for (int ks = 0; ks < BK; ks += 32) {
            const int koff = ks + ((lane >> 4) << 3);
            const int rs = lane & 15;
            bf16x8 af[4], bf[4];
            #pragma unroll
            for (int i = 0; i < 4; ++i) {
                af[i] = *(const bf16x8*)&As[wm + i * 16 + rs][koff];
                bf[i] = *(const bf16x8*)&Bs[wn + i * 16 + rs][koff];
            }
            #pragma unroll
            for (int i = 0; i < 4; ++i)
                #pragma unroll
                for (int j = 0; j < 4; ++j)
                    acc[i][j] = __builtin_amdgcn_mfma_f32_16x16x32_bf16(
                        af[i], bf[j], acc[i][j], 0, 0, 0);
        }
        __syncthreads();
    }

    const int rbase = m0 + wm + ((lane >> 4) << 2);
    const int cbase = n0 + wn + (lane & 15);

    #pragma unroll
    for (int j = 0; j < 4; ++j) {
        const int col = cbase + j * 16;
        const float bv = bias[col];
        #pragma unroll
        for (int i = 0; i < 4; ++i) {
            const int row0 = rbase + i * 16;
            #pragma unroll
            for (int r = 0; r < 4; ++r)
                out[(size_t)(row0 + r) * DIM + col] = acc[i][j][r] + bv;
        }
    }
}

// ---------------------------------------------------------------------------
extern "C" void kernel_launch(void* const* d_in, const int* in_sizes, int n_in,
                              void* d_out, int out_size, void* d_ws, size_t ws_size,
                              hipStream_t stream)
{
    const float* x      = (const float*)d_in[0];
    const float* qkv_w  = (const float*)d_in[1];
    const float* proj_w = (const float*)d_in[2];
    const float* proj_b = (const float*)d_in[3];

    const size_t headsz = (size_t)NHEADS * SEQ * HD;       // 3,145,728
    char* p = (char*)d_ws;
    ushort* Qb    = (ushort*)p;                 p += headsz * 2;
    ushort* Kb    = (ushort*)p;                 p += headsz * 2;
    ushort* Vp    = (ushort*)p;                 p += headsz * 2;
    ushort* AO    = (ushort*)p;                 p += (size_t)SEQ * DIM * 2;
    float*  Opart = (float*)p;                  p += (size_t)KSPLIT * headsz * 4;
    float*  lpart = (float*)p;                  p += (size_t)KSPLIT * NHEADS * SEQ * 4;
    float2* tab   = (float2*)p;                 p += (size_t)SEQ * 32 * sizeof(float2);
    ushort* xb    = (ushort*)p;                 p += (size_t)SEQ * DIM * 2;       // 6.3 MB
    ushort* qwb   = (ushort*)p;                 p += (size_t)3 * DIM * DIM * 2;   // 3.5 MB
    ushort* pwb   = (ushort*)p;                                                  // 1.2 MB
    float*  out   = (float*)d_out;

    rope_tab_k<<<(SEQ * 32) / 256, 256, 0, stream>>>(tab);
    cvt_bf16<<<(SEQ * DIM / 4) / 256, 256, 0, stream>>>(x, xb, SEQ * DIM / 4);
    cvt_bf16<<<(3 * DIM * DIM / 4) / 256, 256, 0, stream>>>(qkv_w, qwb, 3 * DIM * DIM / 4);
    cvt_bf16<<<(DIM * DIM / 4) / 256, 256, 0, stream>>>(proj_w, pwb, DIM * DIM / 4);

    gemm_qkv<<<dim3(3 * DIM / 128, SEQ / 128), 256, 0, stream>>>(
        xb, qwb, tab, Qb, Kb, Vp);

    flash_mfma<<<dim3(SEQ / 128, NHEADS, KSPLIT), 256, 0, stream>>>(
        Qb, Kb, Vp, Opart, lpart);

    merge_k<<<(NHEADS * SEQ * 16) / 256, 256, 0, stream>>>(Opart, lpart, AO);

    gemm_proj<<<dim3(DIM / 128, SEQ / 128), 256, 0, stream>>>(
        AO, pwb, proj_b, out);
}

// Round 12
// 264.789 us; speedup vs baseline: 2.5239x; 2.5239x over previous
//
#include <hip/hip_runtime.h>
#include <hip/hip_bf16.h>
#include <math.h>

#define DIM 768
#define NHEADS 12
#define HD 64
#define SEQ 4096
#define KSPLIT 4

typedef __bf16 bf16x8 __attribute__((ext_vector_type(8)));
typedef float f32x4 __attribute__((ext_vector_type(4)));

// Native bf16 convert (RNE; gfx950 HW cvt, compiler may pack pairs)
__device__ inline ushort f2bf(float f) {
    __bf16 b = (__bf16)f;
    union { __bf16 b; ushort u; } v; v.b = b;
    return v.u;
}

// ---------------------------------------------------------------------------
// f32 -> bf16 bulk convert (16B loads / 8B stores), exact-grid.
// ---------------------------------------------------------------------------
__global__ __launch_bounds__(256)
void cvt_bf16(const float* __restrict__ src, ushort* __restrict__ dst, int n4)
{
    const int i = blockIdx.x * 256 + threadIdx.x;
    if (i >= n4) return;
    const float4 v = ((const float4*)src)[i];
    ushort4 w;
    w.x = f2bf(v.x); w.y = f2bf(v.y); w.z = f2bf(v.z); w.w = f2bf(v.w);
    ((ushort4*)dst)[i] = w;
}

// ---------------------------------------------------------------------------
// RoPE table: tab[n][j] = (cos, sin) of n * 10000^(-j/32), j in [0,32).
// ---------------------------------------------------------------------------
__global__ __launch_bounds__(256)
void rope_tab_k(float2* __restrict__ tab)
{
    const int idx = blockIdx.x * 256 + threadIdx.x;   // 4096*32
    const int j = idx & 31;
    const int n = idx >> 5;
    const float invf = (float)pow(10000.0, -(double)j / 32.0);
    const float ang  = (float)n * invf;               // f32 (matches ref freqs)
    double s, c;
    sincos((double)ang, &s, &c);
    tab[idx] = make_float2((float)c, (float)s);
}

// ---------------------------------------------------------------------------
// QKV GEMM (bf16 in) + fused RoPE + layout:
//   t=0 (q): RoPE, *0.125, bf16 -> Qb[h][n][d]
//   t=1 (k): RoPE, bf16 -> Kb[h][n][d]
//   t=2 (v): bf16 -> Vp[h][d][64T + s], key-slot permuted (flash P order)
// ---------------------------------------------------------------------------
__global__ __launch_bounds__(256)
void gemm_qkv(const ushort* __restrict__ A, const ushort* __restrict__ B,
              const float2* __restrict__ tab,
              ushort* __restrict__ Qb, ushort* __restrict__ Kb,
              ushort* __restrict__ Vp)
{
    constexpr int BM = 128, BN = 128, BK = 64, PAD = 8;
    __shared__ ushort Ah[BM][BK + PAD];
    __shared__ ushort Bh[BN][BK + PAD];

    const int t    = threadIdx.x;
    const int lane = t & 63;
    const int wv   = t >> 6;
    const int wm   = (wv >> 1) * 64;
    const int wn   = (wv & 1) * 64;
    const int m0   = blockIdx.y * BM;
    const int n0   = blockIdx.x * BN;

    f32x4 acc[4][4] = {};

    const int srow = t >> 3;          // 0..31
    const int sseg = (t & 7) * 8;     // bf16 16B chunks

    for (int k0 = 0; k0 < DIM; k0 += BK) {
        #pragma unroll
        for (int i = 0; i < 4; ++i) {
            const int row = srow + i * 32;
            *(float4*)&Ah[row][sseg] =
                *(const float4*)&A[(size_t)(m0 + row) * DIM + k0 + sseg];
            *(float4*)&Bh[row][sseg] =
                *(const float4*)&B[(size_t)(n0 + row) * DIM + k0 + sseg];
        }
        __syncthreads();

        #pragma unroll
        for (int ks = 0; ks < BK; ks += 32) {
            const int koff = ks + ((lane >> 4) << 3);
            const int rs = lane & 15;
            bf16x8 af[4], bf[4];
            #pragma unroll
            for (int i = 0; i < 4; ++i) {
                af[i] = *(const bf16x8*)&Ah[wm + i * 16 + rs][koff];
                bf[i] = *(const bf16x8*)&Bh[wn + i * 16 + rs][koff];
            }
            #pragma unroll
            for (int i = 0; i < 4; ++i)
                #pragma unroll
                for (int j = 0; j < 4; ++j)
                    acc[i][j] = __builtin_amdgcn_mfma_f32_16x16x32_bf16(
                        af[i], bf[j], acc[i][j], 0, 0, 0);
        }
        __syncthreads();
    }

    const int rsel  = lane & 15;
    const int quad  = lane >> 4;
    const int rbase = m0 + wm + (quad << 2);
    const int c0    = n0 + wn;          // 64-aligned -> one (t,h) per wave
    const int tt    = c0 / DIM;
    const int h     = (c0 % DIM) >> 6;

    if (tt == 2) {
        // key kappa (within 64-tile) = 16i + 4quad + r -> slot 16quad + 4r + i
        const int T = (m0 + wm) >> 6;
        #pragma unroll
        for (int j = 0; j < 4; ++j) {
            const int d = rsel + 16 * j;
            ushort vv[16];
            #pragma unroll
            for (int r = 0; r < 4; ++r)
                #pragma unroll
                for (int i = 0; i < 4; ++i)
                    vv[4 * r + i] = f2bf(acc[i][j][r]);
            ushort* dst = &Vp[((size_t)h * HD + d) * SEQ + T * 64 + 16 * quad];
            *(float4*)&dst[0] = *(const float4*)&vv[0];
            *(float4*)&dst[8] = *(const float4*)&vv[8];
        }
    } else {
        ushort* dstb = (tt == 0 ? Qb : Kb) + (size_t)h * SEQ * HD;
        const float qs = (tt == 0) ? 0.125f : 1.0f;
        #pragma unroll
        for (int i = 0; i < 4; ++i)
            #pragma unroll
            for (int r = 0; r < 4; ++r) {
                const int n = rbase + i * 16 + r;
                #pragma unroll
                for (int j = 0; j < 2; ++j) {
                    const float a = acc[i][j][r];
                    const float b = acc[i][j + 2][r];
                    const float2 cs2 = tab[n * 32 + rsel + 16 * j];
                    dstb[(size_t)n * HD + rsel + 16 * j]      = f2bf((a * cs2.x - b * cs2.y) * qs);
                    dstb[(size_t)n * HD + rsel + 16 * j + 32] = f2bf((b * cs2.x + a * cs2.y) * qs);
                }
            }
    }
}

// ---------------------------------------------------------------------------
// MFMA flash attention, LDS-staged K/V, split-K, no-max softmax.
// Block = 4 waves x 32 q-rows = 128 rows. LDS 26.1 KB.
// __launch_bounds__(256, 4): VGPR cap 128 (compiles ~64, no spill).
// r11's (256,6) capped VGPR at ~40 -> scratch spill -> 2.6 GB HBM traffic.
// LDS allows 6 blocks/CU at VGPR<=85; the scheduler fills what fits.
// ---------------------------------------------------------------------------
__global__ __launch_bounds__(256, 4)
void flash_mfma(const ushort* __restrict__ Qb, const ushort* __restrict__ Kb,
                const ushort* __restrict__ Vp,
                float* __restrict__ Opart, float* __restrict__ lpart)
{
    __shared__ ushort Ks[64][68];      // [key][d]
    __shared__ ushort Vs[64][68];      // [d][slot]
    __shared__ ushort Pl[4][16][68];   // per-wave P, [row][slot], reused per mi

    const int t    = threadIdx.x;
    const int lane = t & 63;
    const int wv   = t >> 6;
    const int rsel = lane & 15;
    const int quad = lane >> 4;
    const int h    = blockIdx.y;
    const int part = blockIdx.z;
    const int q0   = blockIdx.x * 128 + wv * 32;
    const int Tbeg = (part * (SEQ / KSPLIT)) >> 6;
    const int Tend = Tbeg + (SEQ / KSPLIT) / 64;

    const int crow = t >> 2;           // 0..63 staging row
    const int ccol = (t & 3) * 16;     // 0/16/32/48 ushorts (2x16B per thread)

    // Q A-frags (persistent)
    bf16x8 aq[2][2];
    #pragma unroll
    for (int mi = 0; mi < 2; ++mi)
        #pragma unroll
        for (int ks = 0; ks < 2; ++ks)
            aq[mi][ks] = *(const bf16x8*)&Qb[((size_t)h * SEQ + q0 + 16 * mi + rsel) * HD
                                             + ks * 32 + quad * 8];

    f32x4 accO[2][4] = {};
    float lsum[2][4] = {};

    for (int T = Tbeg; T < Tend; ++T) {
        __syncthreads();               // prior tile's LDS reads done
        {   // coalesced staging: 4 consecutive threads cover one 128B row
            const ushort* ksrc = &Kb[((size_t)h * SEQ + T * 64 + crow) * HD + ccol];
            *(float4*)&Ks[crow][ccol]     = *(const float4*)&ksrc[0];
            *(float4*)&Ks[crow][ccol + 8] = *(const float4*)&ksrc[8];
            const ushort* vsrc = &Vp[((size_t)h * HD + crow) * SEQ + T * 64 + ccol];
            *(float4*)&Vs[crow][ccol]     = *(const float4*)&vsrc[0];
            *(float4*)&Vs[crow][ccol + 8] = *(const float4*)&vsrc[8];
        }
        __syncthreads();

        // K and V B-frags from LDS (shared across both M-halves)
        bf16x8 bk[4][2], bv[4][2];
        #pragma unroll
        for (int n = 0; n < 4; ++n)
            #pragma unroll
            for (int ks = 0; ks < 2; ++ks) {
                bk[n][ks] = *(const bf16x8*)&Ks[16 * n + rsel][32 * ks + quad * 8];
                bv[n][ks] = *(const bf16x8*)&Vs[16 * n + rsel][32 * ks + quad * 8];
            }

        #pragma unroll
        for (int mi = 0; mi < 2; ++mi) {
            f32x4 accS[4] = {};
            #pragma unroll
            for (int ks = 0; ks < 2; ++ks)
                #pragma unroll
                for (int n = 0; n < 4; ++n)
                    accS[n] = __builtin_amdgcn_mfma_f32_16x16x32_bf16(
                        aq[mi][ks], bk[n][ks], accS[n], 0, 0, 0);

            // P = exp(S); packed write, slot s = 4rsel + n (key = 16n + rsel)
            #pragma unroll
            for (int r = 0; r < 4; ++r) {
                const float p0 = __expf(accS[0][r]);
                const float p1 = __expf(accS[1][r]);
                const float p2 = __expf(accS[2][r]);
                const float p3 = __expf(accS[3][r]);
                ushort4 pw;
                pw.x = f2bf(p0); pw.y = f2bf(p1);
                pw.z = f2bf(p2); pw.w = f2bf(p3);
                *(ushort4*)&Pl[wv][4 * quad + r][4 * rsel] = pw;
                lsum[mi][r] += (p0 + p1) + (p2 + p3);
            }

            // wave-private LDS RAW: drain writes before A-frag reads
            asm volatile("s_waitcnt lgkmcnt(0)" ::: "memory");

            bf16x8 ap[2];
            ap[0] = *(const bf16x8*)&Pl[wv][rsel][quad * 8];
            ap[1] = *(const bf16x8*)&Pl[wv][rsel][32 + quad * 8];
            #pragma unroll
            for (int ks = 0; ks < 2; ++ks)
                #pragma unroll
                for (int j = 0; j < 4; ++j)
                    accO[mi][j] = __builtin_amdgcn_mfma_f32_16x16x32_bf16(
                        ap[ks], bv[j][ks], accO[mi][j], 0, 0, 0);
        }
    }

    // one-time l reduction across rsel lanes
    #pragma unroll
    for (int mi = 0; mi < 2; ++mi)
        #pragma unroll
        for (int r = 0; r < 4; ++r) {
            float s = lsum[mi][r];
            s += __shfl_xor(s, 1);
            s += __shfl_xor(s, 2);
            s += __shfl_xor(s, 4);
            s += __shfl_xor(s, 8);
            lsum[mi][r] = s;
        }

    float* Ob = Opart + ((size_t)part * NHEADS + h) * SEQ * HD;
    float* lb = lpart + ((size_t)part * NHEADS + h) * SEQ;
    #pragma unroll
    for (int mi = 0; mi < 2; ++mi)
        #pragma unroll
        for (int r = 0; r < 4; ++r) {
            const int n = q0 + 16 * mi + 4 * quad + r;
            #pragma unroll
            for (int j = 0; j < 4; ++j)
                Ob[(size_t)n * HD + 16 * j + rsel] = accO[mi][j][r];
            if (rsel == 0) lb[n] = lsum[mi][r];
        }
}

// ---------------------------------------------------------------------------
// Split-K merge: AO[n][h*64+d] = (sum_p Opart) / (sum_p l), bf16.
// ---------------------------------------------------------------------------
__global__ __launch_bounds__(256)
void merge_k(const float* __restrict__ Opart, const float* __restrict__ lpart,
             ushort* __restrict__ AO)
{
    const int idx = blockIdx.x * 256 + threadIdx.x;
    const int dg = idx & 15;
    const int n  = (idx >> 4) & (SEQ - 1);
    const int h  = idx >> 16;

    float4 o = make_float4(0.f, 0.f, 0.f, 0.f);
    float l = 0.f;
    #pragma unroll
    for (int p = 0; p < KSPLIT; ++p) {
        const float4 v = *(const float4*)&Opart[(((size_t)p * NHEADS + h) * SEQ + n) * HD + dg * 4];
        o.x += v.x; o.y += v.y; o.z += v.z; o.w += v.w;
        l += lpart[((size_t)p * NHEADS + h) * SEQ + n];
    }
    const float inv = 1.f / l;
    ushort4 w;
    w.x = f2bf(o.x * inv); w.y = f2bf(o.y * inv);
    w.z = f2bf(o.z * inv); w.w = f2bf(o.w * inv);
    *(ushort4*)&AO[(size_t)n * DIM + h * HD + dg * 4] = w;
}

// ---------------------------------------------------------------------------
// Proj GEMM: out = attnout(bf16) @ proj_wb(bf16)^T + proj_b(f32), f32 out.
// ---------------------------------------------------------------------------
__global__ __launch_bounds__(256)
void gemm_proj(const ushort* __restrict__ A, const ushort* __restrict__ B,
               const float* __restrict__ bias, float* __restrict__ out)
{
    constexpr int BM = 128, BN = 128, BK = 64, PAD = 8;
    __shared__ ushort As[BM][BK + PAD];
    __shared__ ushort Bs[BN][BK + PAD];

    const int t    = threadIdx.x;
    const int lane = t & 63;
    const int wv   = t >> 6;
    const int wm   = (wv >> 1) * 64;
    const int wn   = (wv & 1) * 64;
    const int m0   = blockIdx.y * BM;
    const int n0   = blockIdx.x * BN;

    f32x4 acc[4][4] = {};

    const int srow = t >> 3;
    const int sseg = (t & 7) * 8;

    for (int k0 = 0; k0 < DIM; k0 += BK) {
        #pragma unroll
        for (int i = 0; i < 4; ++i) {
            const int row = srow + i * 32;
            *(float4*)&As[row][sseg] =
                *(const float4*)&A[(size_t)(m0 + row) * DIM + k0 + sseg];
            *(float4*)&Bs[row][sseg] =
                *(const float4*)&B[(size_t)(n0 + row) * DIM + k0 + sseg];
        }
        __syncthreads();

        #pragma unroll
        for (int ks = 0; ks < BK; ks += 32) {
            const int koff = ks + ((lane >> 4) << 3);
            const int rs = lane & 15;
            bf16x8 af[4], bf[4];
            #pragma unroll
            for (int i = 0; i < 4; ++i) {
                af[i] = *(const bf16x8*)&As[wm + i * 16 + rs][koff];
                bf[i] = *(const bf16x8*)&Bs[wn + i * 16 + rs][koff];
            }
            #pragma unroll
            for (int i = 0; i < 4; ++i)
                #pragma unroll
                for (int j = 0; j < 4; ++j)
                    acc[i][j] = __builtin_amdgcn_mfma_f32_16x16x32_bf16(
                        af[i], bf[j], acc[i][j], 0, 0, 0);
        }
        __syncthreads();
    }

    const int rbase = m0 + wm + ((lane >> 4) << 2);
    const int cbase = n0 + wn + (lane & 15);

    #pragma unroll
    for (int j = 0; j < 4; ++j) {
        const int col = cbase + j * 16;
        const float bv = bias[col];
        #pragma unroll
        for (int i = 0; i < 4; ++i) {
            const int row0 = rbase + i * 16;
            #pragma unroll
            for (int r = 0; r < 4; ++r)
                out[(size_t)(row0 + r) * DIM + col] = acc[i][j][r] + bv;
        }
    }
}

// ---------------------------------------------------------------------------
extern "C" void kernel_launch(void* const* d_in, const int* in_sizes, int n_in,
                              void* d_out, int out_size, void* d_ws, size_t ws_size,
                              hipStream_t stream)
{
    const float* x      = (const float*)d_in[0];
    const float* qkv_w  = (const float*)d_in[1];
    const float* proj_w = (const float*)d_in[2];
    const float* proj_b = (const float*)d_in[3];

    const size_t headsz = (size_t)NHEADS * SEQ * HD;       // 3,145,728
    char* p = (char*)d_ws;
    ushort* Qb    = (ushort*)p;                 p += headsz * 2;
    ushort* Kb    = (ushort*)p;                 p += headsz * 2;
    ushort* Vp    = (ushort*)p;                 p += headsz * 2;
    ushort* AO    = (ushort*)p;                 p += (size_t)SEQ * DIM * 2;
    float*  Opart = (float*)p;                  p += (size_t)KSPLIT * headsz * 4;
    float*  lpart = (float*)p;                  p += (size_t)KSPLIT * NHEADS * SEQ * 4;
    float2* tab   = (float2*)p;                 p += (size_t)SEQ * 32 * sizeof(float2);
    ushort* xb    = (ushort*)p;                 p += (size_t)SEQ * DIM * 2;
    ushort* qwb   = (ushort*)p;                 p += (size_t)3 * DIM * DIM * 2;
    ushort* pwb   = (ushort*)p;
    float*  out   = (float*)d_out;

    rope_tab_k<<<(SEQ * 32) / 256, 256, 0, stream>>>(tab);
    cvt_bf16<<<(SEQ * DIM / 4) / 256, 256, 0, stream>>>(x, xb, SEQ * DIM / 4);
    cvt_bf16<<<(3 * DIM * DIM / 4) / 256, 256, 0, stream>>>(qkv_w, qwb, 3 * DIM * DIM / 4);
    cvt_bf16<<<(DIM * DIM / 4) / 256, 256, 0, stream>>>(proj_w, pwb, DIM * DIM / 4);

    gemm_qkv<<<dim3(3 * DIM / 128, SEQ / 128), 256, 0, stream>>>(
        xb, qwb, tab, Qb, Kb, Vp);

    flash_mfma<<<dim3(SEQ / 128, NHEADS, KSPLIT), 256, 0, stream>>>(
        Qb, Kb, Vp, Opart, lpart);

    merge_k<<<(NHEADS * SEQ * 16) / 256, 256, 0, stream>>>(Opart, lpart, AO);

    gemm_proj<<<dim3(DIM / 128, SEQ / 128), 256, 0, stream>>>(
        AO, pwb, proj_b, out);
}

// Round 13
// 229.053 us; speedup vs baseline: 2.9177x; 1.1560x over previous
//
#include <hip/hip_runtime.h>
#include <hip/hip_bf16.h>
#include <math.h>

#define DIM 768
#define NHEADS 12
#define HD 64
#define SEQ 4096
#define KSPLIT 4

typedef __bf16 bf16x8 __attribute__((ext_vector_type(8)));
typedef float f32x4 __attribute__((ext_vector_type(4)));

// Native bf16 convert (RNE) — used outside flash.
__device__ inline ushort f2bf(float f) {
    __bf16 b = (__bf16)f;
    union { __bf16 b; ushort u; } v; v.b = b;
    return v.u;
}

// Manual RNE twiddle — used inside flash (byte-identical to the r10 kernel,
// which measured 93 us; r12's variant regressed to 137 us).
__device__ inline ushort f2bf_tw(float f) {
    union { float f; uint u; } v; v.f = f;
    uint r = v.u + 0x7FFF + ((v.u >> 16) & 1);
    return (ushort)(r >> 16);
}

// ---------------------------------------------------------------------------
// f32 -> bf16 bulk convert (16B loads / 8B stores), exact-grid.
// ---------------------------------------------------------------------------
__global__ __launch_bounds__(256)
void cvt_bf16(const float* __restrict__ src, ushort* __restrict__ dst, int n4)
{
    const int i = blockIdx.x * 256 + threadIdx.x;
    if (i >= n4) return;
    const float4 v = ((const float4*)src)[i];
    ushort4 w;
    w.x = f2bf(v.x); w.y = f2bf(v.y); w.z = f2bf(v.z); w.w = f2bf(v.w);
    ((ushort4*)dst)[i] = w;
}

// ---------------------------------------------------------------------------
// RoPE table: tab[n][j] = (cos, sin) of n * 10000^(-j/32), j in [0,32).
// ---------------------------------------------------------------------------
__global__ __launch_bounds__(256)
void rope_tab_k(float2* __restrict__ tab)
{
    const int idx = blockIdx.x * 256 + threadIdx.x;   // 4096*32
    const int j = idx & 31;
    const int n = idx >> 5;
    const float invf = (float)pow(10000.0, -(double)j / 32.0);
    const float ang  = (float)n * invf;               // f32 (matches ref freqs)
    double s, c;
    sincos((double)ang, &s, &c);
    tab[idx] = make_float2((float)c, (float)s);
}

// ---------------------------------------------------------------------------
// QKV GEMM (bf16 in) + fused RoPE + layout:
//   t=0 (q): RoPE, *0.125, bf16 -> Qb[h][n][d]
//   t=1 (k): RoPE, bf16 -> Kb[h][n][d]
//   t=2 (v): bf16 -> Vp[h][d][64T + s], key-slot permuted (flash P order)
// ---------------------------------------------------------------------------
__global__ __launch_bounds__(256)
void gemm_qkv(const ushort* __restrict__ A, const ushort* __restrict__ B,
              const float2* __restrict__ tab,
              ushort* __restrict__ Qb, ushort* __restrict__ Kb,
              ushort* __restrict__ Vp)
{
    constexpr int BM = 128, BN = 128, BK = 64, PAD = 8;
    __shared__ ushort Ah[BM][BK + PAD];
    __shared__ ushort Bh[BN][BK + PAD];

    const int t    = threadIdx.x;
    const int lane = t & 63;
    const int wv   = t >> 6;
    const int wm   = (wv >> 1) * 64;
    const int wn   = (wv & 1) * 64;
    const int m0   = blockIdx.y * BM;
    const int n0   = blockIdx.x * BN;

    f32x4 acc[4][4] = {};

    const int srow = t >> 3;          // 0..31
    const int sseg = (t & 7) * 8;     // bf16 16B chunks

    for (int k0 = 0; k0 < DIM; k0 += BK) {
        #pragma unroll
        for (int i = 0; i < 4; ++i) {
            const int row = srow + i * 32;
            *(float4*)&Ah[row][sseg] =
                *(const float4*)&A[(size_t)(m0 + row) * DIM + k0 + sseg];
            *(float4*)&Bh[row][sseg] =
                *(const float4*)&B[(size_t)(n0 + row) * DIM + k0 + sseg];
        }
        __syncthreads();

        #pragma unroll
        for (int ks = 0; ks < BK; ks += 32) {
            const int koff = ks + ((lane >> 4) << 3);
            const int rs = lane & 15;
            bf16x8 af[4], bf[4];
            #pragma unroll
            for (int i = 0; i < 4; ++i) {
                af[i] = *(const bf16x8*)&Ah[wm + i * 16 + rs][koff];
                bf[i] = *(const bf16x8*)&Bh[wn + i * 16 + rs][koff];
            }
            #pragma unroll
            for (int i = 0; i < 4; ++i)
                #pragma unroll
                for (int j = 0; j < 4; ++j)
                    acc[i][j] = __builtin_amdgcn_mfma_f32_16x16x32_bf16(
                        af[i], bf[j], acc[i][j], 0, 0, 0);
        }
        __syncthreads();
    }

    const int rsel  = lane & 15;
    const int quad  = lane >> 4;
    const int rbase = m0 + wm + (quad << 2);
    const int c0    = n0 + wn;          // 64-aligned -> one (t,h) per wave
    const int tt    = c0 / DIM;
    const int h     = (c0 % DIM) >> 6;

    if (tt == 2) {
        // key kappa (within 64-tile) = 16i + 4quad + r -> slot 16quad + 4r + i
        const int T = (m0 + wm) >> 6;
        #pragma unroll
        for (int j = 0; j < 4; ++j) {
            const int d = rsel + 16 * j;
            ushort vv[16];
            #pragma unroll
            for (int r = 0; r < 4; ++r)
                #pragma unroll
                for (int i = 0; i < 4; ++i)
                    vv[4 * r + i] = f2bf(acc[i][j][r]);
            ushort* dst = &Vp[((size_t)h * HD + d) * SEQ + T * 64 + 16 * quad];
            *(float4*)&dst[0] = *(const float4*)&vv[0];
            *(float4*)&dst[8] = *(const float4*)&vv[8];
        }
    } else {
        ushort* dstb = (tt == 0 ? Qb : Kb) + (size_t)h * SEQ * HD;
        const float qs = (tt == 0) ? 0.125f : 1.0f;
        #pragma unroll
        for (int i = 0; i < 4; ++i)
            #pragma unroll
            for (int r = 0; r < 4; ++r) {
                const int n = rbase + i * 16 + r;
                #pragma unroll
                for (int j = 0; j < 2; ++j) {
                    const float a = acc[i][j][r];
                    const float b = acc[i][j + 2][r];
                    const float2 cs2 = tab[n * 32 + rsel + 16 * j];
                    dstb[(size_t)n * HD + rsel + 16 * j]      = f2bf((a * cs2.x - b * cs2.y) * qs);
                    dstb[(size_t)n * HD + rsel + 16 * j + 32] = f2bf((b * cs2.x + a * cs2.y) * qs);
                }
            }
    }
}

// ---------------------------------------------------------------------------
// MFMA flash attention — byte-identical to the round-10 version (93 us,
// MfmaUtil 22%, 117 MB HBM). LDS-staged K/V, split-K, no-max softmax.
// Block = 4 waves x 32 q-rows = 128 rows; LDS 34.8 KB; Pl[4][32][68];
// one lgkmcnt drain per tile.
// ---------------------------------------------------------------------------
__global__ __launch_bounds__(256, 4)
void flash_mfma(const ushort* __restrict__ Qb, const ushort* __restrict__ Kb,
                const ushort* __restrict__ Vp,
                float* __restrict__ Opart, float* __restrict__ lpart)
{
    __shared__ ushort Ks[64][68];      // [key][d]
    __shared__ ushort Vs[64][68];      // [d][slot]
    __shared__ ushort Pl[4][32][68];   // per-wave P, [row][slot]

    const int t    = threadIdx.x;
    const int lane = t & 63;
    const int wv   = t >> 6;
    const int rsel = lane & 15;
    const int quad = lane >> 4;
    const int h    = blockIdx.y;
    const int part = blockIdx.z;
    const int q0   = blockIdx.x * 128 + wv * 32;
    const int Tbeg = (part * (SEQ / KSPLIT)) >> 6;
    const int Tend = Tbeg + (SEQ / KSPLIT) / 64;

    const int crow = t >> 2;           // 0..63 staging row
    const int ccol = (t & 3) * 16;     // 0/16/32/48 ushorts (2x16B per thread)

    // Q A-frags (persistent)
    bf16x8 aq[2][2];
    #pragma unroll
    for (int mi = 0; mi < 2; ++mi)
        #pragma unroll
        for (int ks = 0; ks < 2; ++ks)
            aq[mi][ks] = *(const bf16x8*)&Qb[((size_t)h * SEQ + q0 + 16 * mi + rsel) * HD
                                             + ks * 32 + quad * 8];

    f32x4 accO[2][4] = {};
    float lsum[2][4] = {};

    for (int T = Tbeg; T < Tend; ++T) {
        __syncthreads();               // prior tile's LDS reads done
        {   // coalesced staging: 4 consecutive threads cover one 128B row
            const ushort* ksrc = &Kb[((size_t)h * SEQ + T * 64 + crow) * HD + ccol];
            *(float4*)&Ks[crow][ccol]     = *(const float4*)&ksrc[0];
            *(float4*)&Ks[crow][ccol + 8] = *(const float4*)&ksrc[8];
            const ushort* vsrc = &Vp[((size_t)h * HD + crow) * SEQ + T * 64 + ccol];
            *(float4*)&Vs[crow][ccol]     = *(const float4*)&vsrc[0];
            *(float4*)&Vs[crow][ccol + 8] = *(const float4*)&vsrc[8];
        }
        __syncthreads();

        // K and V B-frags from LDS (shared across both M-halves)
        bf16x8 bk[4][2], bv[4][2];
        #pragma unroll
        for (int n = 0; n < 4; ++n)
            #pragma unroll
            for (int ks = 0; ks < 2; ++ks) {
                bk[n][ks] = *(const bf16x8*)&Ks[16 * n + rsel][32 * ks + quad * 8];
                bv[n][ks] = *(const bf16x8*)&Vs[16 * n + rsel][32 * ks + quad * 8];
            }

        #pragma unroll
        for (int mi = 0; mi < 2; ++mi) {
            f32x4 accS[4] = {};
            #pragma unroll
            for (int ks = 0; ks < 2; ++ks)
                #pragma unroll
                for (int n = 0; n < 4; ++n)
                    accS[n] = __builtin_amdgcn_mfma_f32_16x16x32_bf16(
                        aq[mi][ks], bk[n][ks], accS[n], 0, 0, 0);

            // P = exp(S); packed write, slot s = 4rsel + n (key = 16n + rsel)
            #pragma unroll
            for (int r = 0; r < 4; ++r) {
                const float p0 = __expf(accS[0][r]);
                const float p1 = __expf(accS[1][r]);
                const float p2 = __expf(accS[2][r]);
                const float p3 = __expf(accS[3][r]);
                ushort4 pw;
                pw.x = f2bf_tw(p0); pw.y = f2bf_tw(p1);
                pw.z = f2bf_tw(p2); pw.w = f2bf_tw(p3);
                *(ushort4*)&Pl[wv][16 * mi + 4 * quad + r][4 * rsel] = pw;
                lsum[mi][r] += (p0 + p1) + (p2 + p3);
            }
        }

        // wave-private LDS RAW: drain writes before A-frag reads (once/tile)
        asm volatile("s_waitcnt lgkmcnt(0)" ::: "memory");

        #pragma unroll
        for (int mi = 0; mi < 2; ++mi) {
            bf16x8 ap[2];
            ap[0] = *(const bf16x8*)&Pl[wv][16 * mi + rsel][quad * 8];
            ap[1] = *(const bf16x8*)&Pl[wv][16 * mi + rsel][32 + quad * 8];
            #pragma unroll
            for (int ks = 0; ks < 2; ++ks)
                #pragma unroll
                for (int j = 0; j < 4; ++j)
                    accO[mi][j] = __builtin_amdgcn_mfma_f32_16x16x32_bf16(
                        ap[ks], bv[j][ks], accO[mi][j], 0, 0, 0);
        }
    }

    // one-time l reduction across rsel lanes
    #pragma unroll
    for (int mi = 0; mi < 2; ++mi)
        #pragma unroll
        for (int r = 0; r < 4; ++r) {
            float s = lsum[mi][r];
            s += __shfl_xor(s, 1);
            s += __shfl_xor(s, 2);
            s += __shfl_xor(s, 4);
            s += __shfl_xor(s, 8);
            lsum[mi][r] = s;
        }

    float* Ob = Opart + ((size_t)part * NHEADS + h) * SEQ * HD;
    float* lb = lpart + ((size_t)part * NHEADS + h) * SEQ;
    #pragma unroll
    for (int mi = 0; mi < 2; ++mi)
        #pragma unroll
        for (int r = 0; r < 4; ++r) {
            const int n = q0 + 16 * mi + 4 * quad + r;
            #pragma unroll
            for (int j = 0; j < 4; ++j)
                Ob[(size_t)n * HD + 16 * j + rsel] = accO[mi][j][r];
            if (rsel == 0) lb[n] = lsum[mi][r];
        }
}

// ---------------------------------------------------------------------------
// Split-K merge: AO[n][h*64+d] = (sum_p Opart) / (sum_p l), bf16.
// ---------------------------------------------------------------------------
__global__ __launch_bounds__(256)
void merge_k(const float* __restrict__ Opart, const float* __restrict__ lpart,
             ushort* __restrict__ AO)
{
    const int idx = blockIdx.x * 256 + threadIdx.x;
    const int dg = idx & 15;
    const int n  = (idx >> 4) & (SEQ - 1);
    const int h  = idx >> 16;

    float4 o = make_float4(0.f, 0.f, 0.f, 0.f);
    float l = 0.f;
    #pragma unroll
    for (int p = 0; p < KSPLIT; ++p) {
        const float4 v = *(const float4*)&Opart[(((size_t)p * NHEADS + h) * SEQ + n) * HD + dg * 4];
        o.x += v.x; o.y += v.y; o.z += v.z; o.w += v.w;
        l += lpart[((size_t)p * NHEADS + h) * SEQ + n];
    }
    const float inv = 1.f / l;
    ushort4 w;
    w.x = f2bf(o.x * inv); w.y = f2bf(o.y * inv);
    w.z = f2bf(o.z * inv); w.w = f2bf(o.w * inv);
    *(ushort4*)&AO[(size_t)n * DIM + h * HD + dg * 4] = w;
}

// ---------------------------------------------------------------------------
// Proj GEMM: out = attnout(bf16) @ proj_wb(bf16)^T + proj_b(f32), f32 out.
// ---------------------------------------------------------------------------
__global__ __launch_bounds__(256)
void gemm_proj(const ushort* __restrict__ A, const ushort* __restrict__ B,
               const float* __restrict__ bias, float* __restrict__ out)
{
    constexpr int BM = 128, BN = 128, BK = 64, PAD = 8;
    __shared__ ushort As[BM][BK + PAD];
    __shared__ ushort Bs[BN][BK + PAD];

    const int t    = threadIdx.x;
    const int lane = t & 63;
    const int wv   = t >> 6;
    const int wm   = (wv >> 1) * 64;
    const int wn   = (wv & 1) * 64;
    const int m0   = blockIdx.y * BM;
    const int n0   = blockIdx.x * BN;

    f32x4 acc[4][4] = {};

    const int srow = t >> 3;
    const int sseg = (t & 7) * 8;

    for (int k0 = 0; k0 < DIM; k0 += BK) {
        #pragma unroll
        for (int i = 0; i < 4; ++i) {
            const int row = srow + i * 32;
            *(float4*)&As[row][sseg] =
                *(const float4*)&A[(size_t)(m0 + row) * DIM + k0 + sseg];
            *(float4*)&Bs[row][sseg] =
                *(const float4*)&B[(size_t)(n0 + row) * DIM + k0 + sseg];
        }
        __syncthreads();

        #pragma unroll
        for (int ks = 0; ks < BK; ks += 32) {
            const int koff = ks + ((lane >> 4) << 3);
            const int rs = lane & 15;
            bf16x8 af[4], bf[4];
            #pragma unroll
            for (int i = 0; i < 4; ++i) {
                af[i] = *(const bf16x8*)&As[wm + i * 16 + rs][koff];
                bf[i] = *(const bf16x8*)&Bs[wn + i * 16 + rs][koff];
            }
            #pragma unroll
            for (int i = 0; i < 4; ++i)
                #pragma unroll
                for (int j = 0; j < 4; ++j)
                    acc[i][j] = __builtin_amdgcn_mfma_f32_16x16x32_bf16(
                        af[i], bf[j], acc[i][j], 0, 0, 0);
        }
        __syncthreads();
    }

    const int rbase = m0 + wm + ((lane >> 4) << 2);
    const int cbase = n0 + wn + (lane & 15);

    #pragma unroll
    for (int j = 0; j < 4; ++j) {
        const int col = cbase + j * 16;
        const float bv = bias[col];
        #pragma unroll
        for (int i = 0; i < 4; ++i) {
            const int row0 = rbase + i * 16;
            #pragma unroll
            for (int r = 0; r < 4; ++r)
                out[(size_t)(row0 + r) * DIM + col] = acc[i][j][r] + bv;
        }
    }
}

// ---------------------------------------------------------------------------
extern "C" void kernel_launch(void* const* d_in, const int* in_sizes, int n_in,
                              void* d_out, int out_size, void* d_ws, size_t ws_size,
                              hipStream_t stream)
{
    const float* x      = (const float*)d_in[0];
    const float* qkv_w  = (const float*)d_in[1];
    const float* proj_w = (const float*)d_in[2];
    const float* proj_b = (const float*)d_in[3];

    const size_t headsz = (size_t)NHEADS * SEQ * HD;       // 3,145,728
    char* p = (char*)d_ws;
    ushort* Qb    = (ushort*)p;                 p += headsz * 2;
    ushort* Kb    = (ushort*)p;                 p += headsz * 2;
    ushort* Vp    = (ushort*)p;                 p += headsz * 2;
    ushort* AO    = (ushort*)p;                 p += (size_t)SEQ * DIM * 2;
    float*  Opart = (float*)p;                  p += (size_t)KSPLIT * headsz * 4;
    float*  lpart = (float*)p;                  p += (size_t)KSPLIT * NHEADS * SEQ * 4;
    float2* tab   = (float2*)p;                 p += (size_t)SEQ * 32 * sizeof(float2);
    ushort* xb    = (ushort*)p;                 p += (size_t)SEQ * DIM * 2;
    ushort* qwb   = (ushort*)p;                 p += (size_t)3 * DIM * DIM * 2;
    ushort* pwb   = (ushort*)p;
    float*  out   = (float*)d_out;

    rope_tab_k<<<(SEQ * 32) / 256, 256, 0, stream>>>(tab);
    cvt_bf16<<<(SEQ * DIM / 4) / 256, 256, 0, stream>>>(x, xb, SEQ * DIM / 4);
    cvt_bf16<<<(3 * DIM * DIM / 4) / 256, 256, 0, stream>>>(qkv_w, qwb, 3 * DIM * DIM / 4);
    cvt_bf16<<<(DIM * DIM / 4) / 256, 256, 0, stream>>>(proj_w, pwb, DIM * DIM / 4);

    gemm_qkv<<<dim3(3 * DIM / 128, SEQ / 128), 256, 0, stream>>>(
        xb, qwb, tab, Qb, Kb, Vp);

    flash_mfma<<<dim3(SEQ / 128, NHEADS, KSPLIT), 256, 0, stream>>>(
        Qb, Kb, Vp, Opart, lpart);

    merge_k<<<(NHEADS * SEQ * 16) / 256, 256, 0, stream>>>(Opart, lpart, AO);

    gemm_proj<<<dim3(DIM / 128, SEQ / 128), 256, 0, stream>>>(
        AO, pwb, proj_b, out);
}